// Round 7
// baseline (68.079 us; speedup 1.0000x reference)
//
#include <hip/hip_runtime.h>

// DarkNet53 grid decode, barrier-free wave-local transpose, deep pipeline.
//   in : [B=32, A*ATTR=255, 76, 76] f32   (c = a*85 + attr)
//   out: [B, A*76*76, 85] f32
// Each wave owns CPW=4 chunks of 16 spatial positions: ALL 24 dwordx4 loads
// issued up front (~24KB in flight per wave), then per chunk: transform
// attrs 0-4, transpose via wave-private 5440B LDS (within-wave dep -> no
// __syncthreads), contiguous nt float4 stores.

#define A_     3
#define ATTR_  85
#define GW_    76
#define SP_    (76 * 76)    // 5776 = 361 chunks of 16  (exact, no tail)
#define NCHUNK 361
#define WAVES  4            // per block
#define CPW    4            // chunks per wave (software pipeline depth)
#define NT     256

typedef float f32x4 __attribute__((ext_vector_type(4)));

__global__ __launch_bounds__(NT) void darknet_decode_kernel(
    const float* __restrict__ in,
    const float* __restrict__ anchors,
    float* __restrict__ out) {

    const int plane = blockIdx.y;            // b*A + a
    const int a     = plane % A_;
    const int wv    = threadIdx.x >> 6;      // wave id 0..3
    const int l     = threadIdx.x & 63;      // lane
    const int al    = l >> 2;                // attr sub-index 0..15
    const int pq    = l & 3;                 // position quad 0..3

    __shared__ float lds[WAVES * 16 * ATTR_];     // 5440B per wave
    float* __restrict__ wl = lds + wv * (16 * ATTR_);

    const float aw = anchors[2 * a]     * 8.0f;
    const float ah = anchors[2 * a + 1] * 8.0f;

    const float* __restrict__ inp = in + (size_t)plane * ((size_t)ATTR_ * SP_);
    const int c0 = blockIdx.x * (WAVES * CPW) + wv * CPW;   // plane-local chunk

    // ---- issue ALL loads for all CPW chunks up front (up to 24 in flight) ----
    f32x4 v[CPW][6];
    #pragma unroll
    for (int j = 0; j < CPW; ++j) {
        const int c = c0 + j;                // wave-uniform
        if (c < NCHUNK) {
            const float* p = inp + c * 16 + 4 * pq;
            #pragma unroll
            for (int it = 0; it < 5; ++it)
                v[j][it] = *reinterpret_cast<const f32x4*>(p + (size_t)(16 * it + al) * SP_);
            if (al < 5)
                v[j][5] = *reinterpret_cast<const f32x4*>(p + (size_t)(80 + al) * SP_);
        }
    }

    // ---- per chunk: transform -> LDS transpose -> linear nt store ----
    #pragma unroll
    for (int j = 0; j < CPW; ++j) {
        const int c = c0 + j;
        if (c < NCHUNK) {
            // transform specials (attrs 0..4 live in v[j][0] on lanes al<5)
            if (al < 5) {
                #pragma unroll
                for (int k = 0; k < 4; ++k) {
                    const int s = c * 16 + 4 * pq + k;
                    const float x = v[j][0][k];
                    float r;
                    if (al == 0)      r = 1.0f / (1.0f + __expf(-x));
                    else if (al == 1) r = (1.0f / (1.0f + __expf(-x)) + (float)(s % GW_)) * 8.0f;
                    else if (al == 2) r = (1.0f / (1.0f + __expf(-x)) + (float)(s / GW_)) * 8.0f;
                    else if (al == 3) r = aw * __expf(x);
                    else              r = ah * __expf(x);
                    v[j][0][k] = r;
                }
            }

            // scatter into wave-private LDS [pos][attr]
            #pragma unroll
            for (int it = 0; it < 5; ++it) {
                const int attr = 16 * it + al;
                #pragma unroll
                for (int k = 0; k < 4; ++k)
                    wl[(4 * pq + k) * ATTR_ + attr] = v[j][it][k];
            }
            if (al < 5) {
                const int attr = 80 + al;
                #pragma unroll
                for (int k = 0; k < 4; ++k)
                    wl[(4 * pq + k) * ATTR_ + attr] = v[j][5][k];
            }

            // linear LDS read (340 f32x4) + contiguous nt stores
            const f32x4* __restrict__ wl4 = reinterpret_cast<const f32x4*>(wl);
            f32x4* __restrict__ op4 = reinterpret_cast<f32x4*>(
                out + ((size_t)plane * SP_ + (size_t)c * 16) * ATTR_);
            f32x4 t[6];
            #pragma unroll
            for (int it = 0; it < 5; ++it) t[it] = wl4[l + 64 * it];
            if (l < 20) t[5] = wl4[l + 320];
            #pragma unroll
            for (int it = 0; it < 5; ++it)
                __builtin_nontemporal_store(t[it], &op4[l + 64 * it]);
            if (l < 20)
                __builtin_nontemporal_store(t[5], &op4[l + 320]);
        }
    }
}

extern "C" void kernel_launch(void* const* d_in, const int* in_sizes, int n_in,
                              void* d_out, int out_size, void* d_ws, size_t ws_size,
                              hipStream_t stream) {
    const float* features = (const float*)d_in[0];
    const float* anchors  = (const float*)d_in[1];
    float* out = (float*)d_out;

    const int chunks_per_block = WAVES * CPW;                          // 16
    const int bx = (NCHUNK + chunks_per_block - 1) / chunks_per_block; // 23
    dim3 grid(bx, 32 * A_);
    darknet_decode_kernel<<<grid, NT, 0, stream>>>(features, anchors, out);
}

// Round 8
// 65.683 us; speedup vs baseline: 1.0365x; 1.0365x over previous
//
#include <hip/hip_runtime.h>

// DarkNet53 grid decode, barrier-free wave-local transpose.  (best config: R6)
//   in : [B=32, A*ATTR=255, 76, 76] f32   (c = a*85 + attr)
//   out: [B, A*76*76, 85] f32
// Each wave owns a 16-spatial-position chunk: loads 85 attr rows (64B
// segments), transforms attrs 0-4, transposes via its private 5440B LDS
// region (within-wave dep -> lgkmcnt only, NO __syncthreads), then writes
// one contiguous 5440B output chunk with nt float4 stores.
// CPW=2: the two chunks' 64B read segments are adjacent -> full 128B lines.
// (CPW=4 regressed: compiler serializes the load batch, VGPR 60 not ~120.)

#define A_     3
#define ATTR_  85
#define GW_    76
#define SP_    (76 * 76)    // 5776 = 361 chunks of 16  (exact, no tail)
#define NCHUNK 361
#define WAVES  4            // per block
#define CPW    2            // chunks per wave (software pipeline depth)
#define NT     256

typedef float f32x4 __attribute__((ext_vector_type(4)));

__global__ __launch_bounds__(NT) void darknet_decode_kernel(
    const float* __restrict__ in,
    const float* __restrict__ anchors,
    float* __restrict__ out) {

    const int plane = blockIdx.y;            // b*A + a
    const int a     = plane % A_;
    const int wv    = threadIdx.x >> 6;      // wave id 0..3
    const int l     = threadIdx.x & 63;      // lane
    const int al    = l >> 2;                // attr sub-index 0..15
    const int pq    = l & 3;                 // position quad 0..3

    __shared__ float lds[WAVES * 16 * ATTR_];     // 5440B per wave
    float* __restrict__ wl = lds + wv * (16 * ATTR_);

    const float aw = anchors[2 * a]     * 8.0f;
    const float ah = anchors[2 * a + 1] * 8.0f;

    const float* __restrict__ inp = in + (size_t)plane * ((size_t)ATTR_ * SP_);
    const int c0 = blockIdx.x * (WAVES * CPW) + wv * CPW;   // plane-local chunk

    // ---- issue ALL loads for both chunks up front (up to 12 in flight) ----
    f32x4 v[CPW][6];
    #pragma unroll
    for (int j = 0; j < CPW; ++j) {
        const int c = c0 + j;                // wave-uniform
        if (c < NCHUNK) {
            const float* p = inp + c * 16 + 4 * pq;
            #pragma unroll
            for (int it = 0; it < 5; ++it)
                v[j][it] = *reinterpret_cast<const f32x4*>(p + (size_t)(16 * it + al) * SP_);
            if (al < 5)
                v[j][5] = *reinterpret_cast<const f32x4*>(p + (size_t)(80 + al) * SP_);
        }
    }

    // ---- per chunk: transform -> LDS transpose -> linear nt store ----
    #pragma unroll
    for (int j = 0; j < CPW; ++j) {
        const int c = c0 + j;
        if (c < NCHUNK) {
            // transform specials (attrs 0..4 live in v[j][0] on lanes al<5)
            if (al < 5) {
                #pragma unroll
                for (int k = 0; k < 4; ++k) {
                    const int s = c * 16 + 4 * pq + k;
                    const float x = v[j][0][k];
                    float r;
                    if (al == 0)      r = 1.0f / (1.0f + __expf(-x));
                    else if (al == 1) r = (1.0f / (1.0f + __expf(-x)) + (float)(s % GW_)) * 8.0f;
                    else if (al == 2) r = (1.0f / (1.0f + __expf(-x)) + (float)(s / GW_)) * 8.0f;
                    else if (al == 3) r = aw * __expf(x);
                    else              r = ah * __expf(x);
                    v[j][0][k] = r;
                }
            }

            // scatter into wave-private LDS [pos][attr]
            #pragma unroll
            for (int it = 0; it < 5; ++it) {
                const int attr = 16 * it + al;
                #pragma unroll
                for (int k = 0; k < 4; ++k)
                    wl[(4 * pq + k) * ATTR_ + attr] = v[j][it][k];
            }
            if (al < 5) {
                const int attr = 80 + al;
                #pragma unroll
                for (int k = 0; k < 4; ++k)
                    wl[(4 * pq + k) * ATTR_ + attr] = v[j][5][k];
            }

            // linear LDS read (340 f32x4) + contiguous nt stores
            const f32x4* __restrict__ wl4 = reinterpret_cast<const f32x4*>(wl);
            f32x4* __restrict__ op4 = reinterpret_cast<f32x4*>(
                out + ((size_t)plane * SP_ + (size_t)c * 16) * ATTR_);
            f32x4 t[6];
            #pragma unroll
            for (int it = 0; it < 5; ++it) t[it] = wl4[l + 64 * it];
            if (l < 20) t[5] = wl4[l + 320];
            #pragma unroll
            for (int it = 0; it < 5; ++it)
                __builtin_nontemporal_store(t[it], &op4[l + 64 * it]);
            if (l < 20)
                __builtin_nontemporal_store(t[5], &op4[l + 320]);
        }
    }
}

extern "C" void kernel_launch(void* const* d_in, const int* in_sizes, int n_in,
                              void* d_out, int out_size, void* d_ws, size_t ws_size,
                              hipStream_t stream) {
    const float* features = (const float*)d_in[0];
    const float* anchors  = (const float*)d_in[1];
    float* out = (float*)d_out;

    const int chunks_per_block = WAVES * CPW;                     // 8
    const int bx = (NCHUNK + chunks_per_block - 1) / chunks_per_block;  // 46
    dim3 grid(bx, 32 * A_);
    darknet_decode_kernel<<<grid, NT, 0, stream>>>(features, anchors, out);
}